// Round 12
// baseline (153.008 us; speedup 1.0000x reference)
//
#include <hip/hip_runtime.h>
#include <hip/hip_bf16.h>

typedef __attribute__((ext_vector_type(8))) short bf16x8;
typedef __attribute__((ext_vector_type(4))) float f32x4;
typedef __attribute__((ext_vector_type(8))) unsigned short u16x8;
typedef const __attribute__((address_space(1))) void gvoid_t;
typedef __attribute__((address_space(3))) void lvoid_t;

#define ANGLE_COS 0.8775825618903728f  // cos(0.5)
#define ANGLE_SIN 0.4794255386042030f  // sin(0.5)
#define LOG2E 1.4426950408889634f

static __device__ __forceinline__ unsigned short f2bf(float x) {
  union { float f; unsigned u; } v; v.f = x;
  unsigned r = v.u + 0x7FFFu + ((v.u >> 16) & 1u);  // RNE
  return (unsigned short)(r >> 16);
}

static __device__ __forceinline__ float exp2_hw(float x) {
  return __builtin_amdgcn_exp2f(x);  // v_exp_f32: D = 2^S0
}

// ---- single-pass colprep: whole column in registers, one read of w.
// Outputs colinv and bf16 w_norm*log2e in granule layout: granule (q,c) = 16B
// of d = q*8..q*8+7 for column c at wbn + (q*CT + c)*8 shorts.
__global__ __launch_bounds__(256) void colprep_kernel(
    const float* __restrict__ w, float* __restrict__ colinv,
    unsigned short* __restrict__ wbn, int C, int CT) {
  const int c = blockIdx.x * 256 + threadIdx.x;
  if (c >= CT) return;
  if (c >= C) {  // pad columns -> zeros (2^0=1, subtracted in finalize)
    colinv[c] = 0.f;
    u16x8 z;
    #pragma unroll
    for (int j = 0; j < 8; ++j) z[j] = 0;
    #pragma unroll
    for (int q = 0; q < 16; ++q) *(u16x8*)(wbn + ((size_t)q * CT + c) * 8) = z;
    return;
  }
  float col[128];
  float s = 0.f;
  #pragma unroll
  for (int d = 0; d < 128; ++d) {
    col[d] = w[(size_t)d * C + c];
    s += col[d] * col[d];
  }
  const float inv = 1.0f / sqrtf(s);
  colinv[c] = inv;
  const float invl = inv * LOG2E;
  #pragma unroll
  for (int q = 0; q < 16; ++q) {
    u16x8 g;
    #pragma unroll
    for (int j = 0; j < 8; ++j) g[j] = f2bf(col[q * 8 + j] * invl);
    *(u16x8*)(wbn + ((size_t)q * CT + c) * 8) = g;
  }
}

// ---- colnorm only (fallback path when ws can't hold wbn) ----
__global__ void colnorm_kernel(const float* __restrict__ w, float* __restrict__ colinv, int C) {
  int c = blockIdx.x * 256 + threadIdx.x;
  if (c >= C) return;
  float s = 0.f;
  #pragma unroll 8
  for (int d = 0; d < 128; ++d) { float v = w[(size_t)d * C + c]; s += v * v; }
  colinv[c] = 1.0f / sqrtf(s);
}

// ---- row-normalize features -> bf16 Fn, store inverse norms ----
__global__ void fnorm_kernel(const float* __restrict__ f, unsigned short* __restrict__ Fn,
                             float* __restrict__ rowinv) {
  const int wave = threadIdx.x >> 6, lane = threadIdx.x & 63;
  const int row = blockIdx.x * 4 + wave;
  const float* fr = f + (size_t)row * 128;
  float x0 = fr[lane], x1 = fr[lane + 64];
  float s = x0 * x0 + x1 * x1;
  #pragma unroll
  for (int m = 32; m; m >>= 1) s += __shfl_xor(s, m);
  float inv = 1.0f / sqrtf(s);
  Fn[(size_t)row * 128 + lane] = f2bf(x0 * inv);
  Fn[(size_t)row * 128 + lane + 64] = f2bf(x1 * inv);
  if (lane == 0) rowinv[row] = inv;
}

// ---- fp32 dot with the target column: ct and cos(theta+m) per row ----
__global__ void tgtdot_kernel(const float* __restrict__ f, const float* __restrict__ w,
                              const int* __restrict__ target, const float* __restrict__ rowinv,
                              const float* __restrict__ colinv, float* __restrict__ ctv,
                              float* __restrict__ cpv, int C) {
  const int wave = threadIdx.x >> 6, lane = threadIdx.x & 63;
  const int row = blockIdx.x * 4 + wave;
  const int t = target[row];
  const float* fr = f + (size_t)row * 128;
  float s = fr[lane] * w[(size_t)lane * C + t] + fr[lane + 64] * w[(size_t)(lane + 64) * C + t];
  #pragma unroll
  for (int m = 32; m; m >>= 1) s += __shfl_xor(s, m);
  if (lane == 0) {
    float ct = s * rowinv[row] * colinv[t];
    ct = fminf(1.f, fmaxf(-1.f, ct));
    float st = sqrtf(fmaxf(0.f, 1.f - ct * ct));
    ctv[row] = ct;
    cpv[row] = ct * ANGLE_COS - st * ANGLE_SIN;
  }
}

// ---- main: R12 geometry — 256 thr / 4 waves, 64-col tile (16 KB LDS),
// rf=2 (32 rows/wave -> 128 rows/block), grid (1563, 16) = 25008 blocks.
// Rationale: R11's 512-thr / 32KB blocks were barrier-lockstepped with only
// ~2 resident/CU -> no phase diversity, MfmaUtil stuck ~32%. Smaller blocks
// give up to 8 blocks/CU = independent streams; staging of one overlaps
// compute of others. XCD swizzle: a col-tile's 16 row-groups consecutive on
// one XCD; per-XCD wbn slice 3.2MB < 4MB L2.
template <int PREP, int ATOMIC>
__global__ __launch_bounds__(256) void arc_main_kernel(
    const float* __restrict__ w, const float* __restrict__ colinv,
    const unsigned short* __restrict__ wbn, const unsigned short* __restrict__ Fn,
    float* __restrict__ out_part, int C, int CT, int nrows) {
  __shared__ __align__(16) char smem[16384];
  unsigned short* Bt = (unsigned short*)smem;
  float* Rs = (float*)smem;  // reduce scratch, reused after barrier
  const int tid = threadIdx.x;

  // bijective XCD swizzle: total = nx*16 (divisible by 8).
  const int nx = gridDim.x;
  const int i = blockIdx.x + nx * blockIdx.y;  // hw linear id (x fastest)
  const int v = (i & 7) * (nx * 2) + (i >> 3); // XCD-contiguous virtual id
  const int vx = v >> 4;                       // col-tile (64 cols)
  const int vy = v & 15;                       // row-group (128 rows)
  const int cbase = vx << 6;

  const int wave = tid >> 6;
  const int lane = tid & 63;
  const int l15 = lane & 15;
  const int lhi = lane >> 4;
  const int ry = nrows >> 4;               // rows per row-group (128)
  const int rowbase = vy * ry + wave * 32; // 32 rows per wave

  if (PREP) {
    // 16 KB linear copy; granule g = q*64+cc (q 0..15, cc 0..63) -> LDS byte
    // g*16. Per wave: g = base + lane (64 | wave-base) -> q uniform, cc=lane:
    // dest = base + lane*16 (required form), source contiguous 1KB.
    #pragma unroll
    for (int k = 0; k < 4; ++k) {
      const int g = k * 256 + tid;
      const int q = g >> 6, cc = g & 63;
      __builtin_amdgcn_global_load_lds(
          (gvoid_t*)(const void*)(wbn + ((size_t)q * CT + cbase + cc) * 8),
          (lvoid_t*)(void*)((char*)Bt + g * 16), 16, 0, 0);
    }
  } else {
    const int c = tid & 63;
    const int dstart = tid >> 6;  // 0..3
    const int gc = cbase + c;
    const bool ok = (gc < C);
    const float cinv = ok ? colinv[gc] * LOG2E : 0.f;
    const float* wp = w + (size_t)dstart * C + gc;
    char* lb = (char*)Bt + c * 16;
    #pragma unroll 8
    for (int s = 0; s < 32; ++s) {
      const int d = dstart + 4 * s;
      float vv = ok ? wp[(size_t)(4 * s) * C] * cinv : 0.f;
      *(unsigned short*)(lb + ((d >> 3) * 1024 + (d & 7) * 2)) = f2bf(vv);
    }
  }

  // A fragments issued BEFORE the barrier: latency hides under staging drain.
  bf16x8 a[2][4];
  {
    const char* base = (const char*)Fn + (size_t)(rowbase + l15) * 256 + lhi * 16;
    #pragma unroll
    for (int rf = 0; rf < 2; ++rf)
      #pragma unroll
      for (int s = 0; s < 4; ++s)
        a[rf][s] = *(const bf16x8*)(base + rf * 4096 + s * 64);
  }
  __syncthreads();

  float psum[2][4];
  #pragma unroll
  for (int rf = 0; rf < 2; ++rf)
    #pragma unroll
    for (int r = 0; r < 4; ++r) psum[rf][r] = 0.f;

  // double-buffered cf pipeline over 4 col-frags (16 cols each)
  bf16x8 bfA[4], bfB[4];
#define LOADB(DST, CF)                                                        \
  {                                                                           \
    const char* bcol = (const char*)Bt + ((CF) * 16 + l15) * 16;              \
    _Pragma("unroll")                                                         \
    for (int s = 0; s < 4; ++s)                                               \
      DST[s] = *(const bf16x8*)(bcol + (s * 4 + lhi) * 1024);                 \
  }
#define COMPUTE(BF)                                                           \
  {                                                                           \
    f32x4 acc0 = (f32x4){0.f, 0.f, 0.f, 0.f};                                 \
    f32x4 acc1 = (f32x4){0.f, 0.f, 0.f, 0.f};                                 \
    __builtin_amdgcn_s_setprio(1);                                            \
    _Pragma("unroll")                                                         \
    for (int s = 0; s < 4; ++s) {                                             \
      acc0 = __builtin_amdgcn_mfma_f32_16x16x32_bf16(a[0][s], BF[s], acc0, 0, 0, 0); \
      acc1 = __builtin_amdgcn_mfma_f32_16x16x32_bf16(a[1][s], BF[s], acc1, 0, 0, 0); \
    }                                                                         \
    __builtin_amdgcn_s_setprio(0);                                            \
    _Pragma("unroll")                                                         \
    for (int r = 0; r < 4; ++r) {                                             \
      psum[0][r] += exp2_hw(acc0[r]);                                         \
      psum[1][r] += exp2_hw(acc1[r]);                                         \
    }                                                                         \
  }
  LOADB(bfA, 0);
  LOADB(bfB, 1);
  COMPUTE(bfA);            // cf 0 (bfB already in flight)
  LOADB(bfA, 2);
  COMPUTE(bfB);            // cf 1
  LOADB(bfB, 3);
  COMPUTE(bfA);            // cf 2
  COMPUTE(bfB);            // cf 3
#undef LOADB
#undef COMPUTE

  // ---- block-level reduce over the 16 l15 lanes sharing each row ----
  // scratch: [row 0..127][stride 20 floats] (10.2 KB; writes worst 2-way
  // conflict = free; reads spread over banks).
  __syncthreads();  // all waves done reading Bt
  #pragma unroll
  for (int rf = 0; rf < 2; ++rf)
    #pragma unroll
    for (int r = 0; r < 4; ++r) {
      const int rowlocal = wave * 32 + rf * 16 + lhi * 4 + r;
      Rs[rowlocal * 20 + l15] = psum[rf][r];
    }
  __syncthreads();
  if (tid < 128) {
    float s = 0.f;
    #pragma unroll
    for (int j = 0; j < 4; ++j) {
      f32x4 vv = *(const f32x4*)&Rs[tid * 20 + j * 4];
      s += vv[0] + vv[1] + vv[2] + vv[3];
    }
    const int row = vy * ry + tid;
    if (ATOMIC) atomicAdd(&out_part[row], s);
    else out_part[(size_t)vx * nrows + row] = s;
  }
}

// ---- combine partials: 8 row-blocks x 8 part-slices ----
__global__ void reduce_kernel(const float* __restrict__ partial, float* __restrict__ rowsum,
                              int nparts, int nrows) {
  const int row = (blockIdx.x & 7) * 256 + threadIdx.x;
  const int slice = blockIdx.x >> 3;
  const int pper = (nparts + 7) / 8;
  const int p0 = slice * pper;
  const int p1 = min(nparts, p0 + pper);
  float s = 0.f;
  #pragma unroll 4
  for (int p = p0; p < p1; ++p) s += partial[(size_t)p * nrows + row];
  atomicAdd(&rowsum[row], s);
}

// ---- finalize: loss = mean( log(down_i) - cosplus_i ) ----
__global__ void finalize_kernel(const float* __restrict__ rowsum, const float* __restrict__ ctv,
                                const float* __restrict__ cpv, float* __restrict__ out,
                                int N, float pad, float invN) {
  const int tid = threadIdx.x;
  float local = 0.f;
  for (int i = tid; i < N; i += 256) {
    float top = __expf(cpv[i]);
    float down = rowsum[i] - pad - __expf(ctv[i]) + top;
    local += __logf(down) - cpv[i];
  }
  #pragma unroll
  for (int m = 32; m; m >>= 1) local += __shfl_xor(local, m);
  __shared__ float red[4];
  if ((tid & 63) == 0) red[tid >> 6] = local;
  __syncthreads();
  if (tid == 0) out[0] = (red[0] + red[1] + red[2] + red[3]) * invN;
}

extern "C" void kernel_launch(void* const* d_in, const int* in_sizes, int n_in,
                              void* d_out, int out_size, void* d_ws, size_t ws_size,
                              hipStream_t stream) {
  const float* features = (const float*)d_in[0];
  const int* target = (const int*)d_in[1];
  const float* w = (const float*)d_in[2];
  float* out = (float*)d_out;

  const int N = in_sizes[1];          // 2048
  const int D = in_sizes[0] / N;      // 128 (layout hardcoded in kernels)
  const int C = in_sizes[2] / D;      // 100000
  (void)D;
  const int nct = (C + 63) / 64;      // 1563 col tiles (64 cols each)
  const int CT = nct * 64;            // padded col count

  char* ws = (char*)d_ws;
  size_t off = 0;
  unsigned short* Fn = (unsigned short*)(ws + off); off += (size_t)N * 128 * 2;
  float* colinv = (float*)(ws + off); off += (size_t)CT * 4;
  float* rowsum = (float*)(ws + off); off += (size_t)N * 4;
  float* rowinv = (float*)(ws + off); off += (size_t)N * 4;
  float* ctv    = (float*)(ws + off); off += (size_t)N * 4;
  float* cpv    = (float*)(ws + off); off += (size_t)N * 4; off = (off + 255) & ~(size_t)255;
  float* partial = (float*)(ws + off);
  const size_t need_store = off + (size_t)nct * N * 4;
  const size_t wbn_off = (need_store + 255) & ~(size_t)255;
  unsigned short* wbn = (unsigned short*)(ws + wbn_off);
  const size_t need_prep = wbn_off + (size_t)CT * 128 * 2;

  const bool use_store = (ws_size >= need_store);
  const bool use_prep = (ws_size >= need_prep);

  (void)hipMemsetAsync(rowsum, 0, (size_t)N * sizeof(float), stream);
  if (use_prep) {
    colprep_kernel<<<(CT + 255) / 256, 256, 0, stream>>>(w, colinv, wbn, C, CT);
  } else {
    colnorm_kernel<<<(C + 255) / 256, 256, 0, stream>>>(w, colinv, C);
  }
  fnorm_kernel<<<N / 4, 256, 0, stream>>>(features, Fn, rowinv);
  tgtdot_kernel<<<N / 4, 256, 0, stream>>>(features, w, target, rowinv, colinv, ctv, cpv, C);

  dim3 grid(nct, 16);
  if (use_prep && use_store) {
    arc_main_kernel<1, 0><<<grid, 256, 0, stream>>>(w, colinv, wbn, Fn, partial, C, CT, N);
    reduce_kernel<<<64, 256, 0, stream>>>(partial, rowsum, nct, N);
  } else if (use_prep) {
    arc_main_kernel<1, 1><<<grid, 256, 0, stream>>>(w, colinv, wbn, Fn, rowsum, C, CT, N);
  } else if (use_store) {
    arc_main_kernel<0, 0><<<grid, 256, 0, stream>>>(w, colinv, wbn, Fn, partial, C, CT, N);
    reduce_kernel<<<64, 256, 0, stream>>>(partial, rowsum, nct, N);
  } else {
    arc_main_kernel<0, 1><<<grid, 256, 0, stream>>>(w, colinv, wbn, Fn, rowsum, C, CT, N);
  }
  finalize_kernel<<<1, 256, 0, stream>>>(rowsum, ctv, cpv, out, N,
                                         (float)(CT - C), 1.0f / (float)N);
}

// Round 13
// 111.102 us; speedup vs baseline: 1.3772x; 1.3772x over previous
//
#include <hip/hip_runtime.h>
#include <hip/hip_bf16.h>

typedef __attribute__((ext_vector_type(8))) short bf16x8;
typedef __attribute__((ext_vector_type(4))) float f32x4;
typedef __attribute__((ext_vector_type(8))) unsigned short u16x8;
typedef const __attribute__((address_space(1))) void gvoid_t;
typedef __attribute__((address_space(3))) void lvoid_t;

#define ANGLE_COS 0.8775825618903728f  // cos(0.5)
#define ANGLE_SIN 0.4794255386042030f  // sin(0.5)
#define LOG2E 1.4426950408889634f

static __device__ __forceinline__ unsigned short f2bf(float x) {
  union { float f; unsigned u; } v; v.f = x;
  unsigned r = v.u + 0x7FFFu + ((v.u >> 16) & 1u);  // RNE
  return (unsigned short)(r >> 16);
}

static __device__ __forceinline__ float exp2_hw(float x) {
  return __builtin_amdgcn_exp2f(x);  // v_exp_f32: D = 2^S0
}

// ---- single-pass colprep: whole column in registers, one read of w.
// Outputs colinv and bf16 w_norm*log2e in granule layout: granule (q,c) = 16B
// of d = q*8..q*8+7 for column c at wbn + (q*CT + c)*8 shorts.
__global__ __launch_bounds__(256) void colprep_kernel(
    const float* __restrict__ w, float* __restrict__ colinv,
    unsigned short* __restrict__ wbn, int C, int CT) {
  const int c = blockIdx.x * 256 + threadIdx.x;
  if (c >= CT) return;
  if (c >= C) {  // pad columns -> zeros (2^0=1, subtracted in finalize)
    colinv[c] = 0.f;
    u16x8 z;
    #pragma unroll
    for (int j = 0; j < 8; ++j) z[j] = 0;
    #pragma unroll
    for (int q = 0; q < 16; ++q) *(u16x8*)(wbn + ((size_t)q * CT + c) * 8) = z;
    return;
  }
  float col[128];
  float s = 0.f;
  #pragma unroll
  for (int d = 0; d < 128; ++d) {
    col[d] = w[(size_t)d * C + c];
    s += col[d] * col[d];
  }
  const float inv = 1.0f / sqrtf(s);
  colinv[c] = inv;
  const float invl = inv * LOG2E;
  #pragma unroll
  for (int q = 0; q < 16; ++q) {
    u16x8 g;
    #pragma unroll
    for (int j = 0; j < 8; ++j) g[j] = f2bf(col[q * 8 + j] * invl);
    *(u16x8*)(wbn + ((size_t)q * CT + c) * 8) = g;
  }
}

// ---- colnorm only (fallback path when ws can't hold wbn) ----
__global__ void colnorm_kernel(const float* __restrict__ w, float* __restrict__ colinv, int C) {
  int c = blockIdx.x * 256 + threadIdx.x;
  if (c >= C) return;
  float s = 0.f;
  #pragma unroll 8
  for (int d = 0; d < 128; ++d) { float v = w[(size_t)d * C + c]; s += v * v; }
  colinv[c] = 1.0f / sqrtf(s);
}

// ---- row-normalize features -> bf16 Fn, store inverse norms ----
__global__ void fnorm_kernel(const float* __restrict__ f, unsigned short* __restrict__ Fn,
                             float* __restrict__ rowinv) {
  const int wave = threadIdx.x >> 6, lane = threadIdx.x & 63;
  const int row = blockIdx.x * 4 + wave;
  const float* fr = f + (size_t)row * 128;
  float x0 = fr[lane], x1 = fr[lane + 64];
  float s = x0 * x0 + x1 * x1;
  #pragma unroll
  for (int m = 32; m; m >>= 1) s += __shfl_xor(s, m);
  float inv = 1.0f / sqrtf(s);
  Fn[(size_t)row * 128 + lane] = f2bf(x0 * inv);
  Fn[(size_t)row * 128 + lane + 64] = f2bf(x1 * inv);
  if (lane == 0) rowinv[row] = inv;
}

// ---- fp32 dot with the target column: ct and cos(theta+m) per row ----
__global__ void tgtdot_kernel(const float* __restrict__ f, const float* __restrict__ w,
                              const int* __restrict__ target, const float* __restrict__ rowinv,
                              const float* __restrict__ colinv, float* __restrict__ ctv,
                              float* __restrict__ cpv, int C) {
  const int wave = threadIdx.x >> 6, lane = threadIdx.x & 63;
  const int row = blockIdx.x * 4 + wave;
  const int t = target[row];
  const float* fr = f + (size_t)row * 128;
  float s = fr[lane] * w[(size_t)lane * C + t] + fr[lane + 64] * w[(size_t)(lane + 64) * C + t];
  #pragma unroll
  for (int m = 32; m; m >>= 1) s += __shfl_xor(s, m);
  if (lane == 0) {
    float ct = s * rowinv[row] * colinv[t];
    ct = fminf(1.f, fmaxf(-1.f, ct));
    float st = sqrtf(fmaxf(0.f, 1.f - ct * ct));
    ctv[row] = ct;
    cpv[row] = ct * ANGLE_COS - st * ANGLE_SIN;
  }
}

// ---- main: R11 geometry (512 thr / 8 waves, rf=2, 128-col tile, grid
// (782,8), VGPR~44) + R13 software-pipelined exp2: at stage k, issue MFMA
// cluster for cf k, THEN exp2 for cf k-1's accs (independent of in-flight
// MFMAs) -> trans pipe overlaps MFMA pipe. R11's serial pipes (21us MFMA +
// 26us VALU + 15us LDS back-to-back = 66us wall) should compress toward
// max(...). R12 lesson: keep big blocks (small blocks doubled fixed costs).
template <int PREP, int ATOMIC>
__global__ __launch_bounds__(512) void arc_main_kernel(
    const float* __restrict__ w, const float* __restrict__ colinv,
    const unsigned short* __restrict__ wbn, const unsigned short* __restrict__ Fn,
    float* __restrict__ out_part, int C, int CT, int nrows) {
  __shared__ __align__(16) char smem[32768];
  unsigned short* Bt = (unsigned short*)smem;
  float* Rs = (float*)smem;  // reduce scratch, reused after barrier
  const int tid = threadIdx.x;

  // bijective XCD swizzle (total = nx*8): each col-tile's 8 row-groups get
  // consecutive virtual ids on one XCD -> tile L2-hot across its stagings.
  const int nx = gridDim.x;
  const int i = blockIdx.x + nx * blockIdx.y;  // hw linear id (x fastest)
  const int v = (i & 7) * nx + (i >> 3);       // XCD-contiguous virtual id
  const int vx = v >> 3;                       // col-tile
  const int vy = v & 7;                        // row-group
  const int cbase = vx << 7;

  const int wave = tid >> 6;
  const int lane = tid & 63;
  const int l15 = lane & 15;
  const int lhi = lane >> 4;
  const int ry = nrows >> 3;               // rows per row-group (256)
  const int rowbase = vy * ry + wave * 32; // 32 rows per wave

  if (PREP) {
    // 32 KB linear copy of pre-scaled bf16 granules; granule g = q*128+cc
    // lands at LDS byte g*16; per-wave dest = base + lane*16 (required form).
    #pragma unroll
    for (int k = 0; k < 4; ++k) {
      const int g = k * 512 + tid;
      const int q = g >> 7, cc = g & 127;
      __builtin_amdgcn_global_load_lds(
          (gvoid_t*)(const void*)(wbn + ((size_t)q * CT + cbase + cc) * 8),
          (lvoid_t*)(void*)((char*)Bt + g * 16), 16, 0, 0);
    }
  } else {
    const int c = tid & 127;
    const int dstart = tid >> 7;  // 0..3
    const int gc = cbase + c;
    const bool ok = (gc < C);
    const float cinv = ok ? colinv[gc] * LOG2E : 0.f;
    const float* wp = w + (size_t)dstart * C + gc;
    char* lb = (char*)Bt + c * 16;
    #pragma unroll 8
    for (int s = 0; s < 32; ++s) {
      const int d = dstart + 4 * s;
      float vv = ok ? wp[(size_t)(4 * s) * C] * cinv : 0.f;
      *(unsigned short*)(lb + ((d >> 3) * 2048 + (d & 7) * 2)) = f2bf(vv);
    }
  }

  // A fragments issued BEFORE the barrier: latency hides under staging drain.
  bf16x8 a[2][4];
  {
    const char* base = (const char*)Fn + (size_t)(rowbase + l15) * 256 + lhi * 16;
    #pragma unroll
    for (int rf = 0; rf < 2; ++rf)
      #pragma unroll
      for (int s = 0; s < 4; ++s)
        a[rf][s] = *(const bf16x8*)(base + rf * 4096 + s * 64);
  }
  __syncthreads();

  float psum[2][4];
  #pragma unroll
  for (int rf = 0; rf < 2; ++rf)
    #pragma unroll
    for (int r = 0; r < 4; ++r) psum[rf][r] = 0.f;

  // software-pipelined cf loop: dbuf B-frags (bfA/bfB) + dbuf accs (P0/P1).
  // Stage k: MFMA(cf k) issues, then exp2(cf k-1) — independent, overlaps.
  bf16x8 bfA[4], bfB[4];
  f32x4 pa0A, pa1A, pa0B, pa1B;
#define LOADB(DST, CF)                                                        \
  {                                                                           \
    const char* bcol = (const char*)Bt + ((CF) * 16 + l15) * 16;              \
    _Pragma("unroll")                                                         \
    for (int s = 0; s < 4; ++s)                                               \
      DST[s] = *(const bf16x8*)(bcol + (s * 4 + lhi) * 2048);                 \
  }
#define MFMAC(P, BF)                                                          \
  {                                                                           \
    pa0##P = (f32x4){0.f, 0.f, 0.f, 0.f};                                     \
    pa1##P = (f32x4){0.f, 0.f, 0.f, 0.f};                                     \
    __builtin_amdgcn_s_setprio(1);                                            \
    _Pragma("unroll")                                                         \
    for (int s = 0; s < 4; ++s) {                                             \
      pa0##P = __builtin_amdgcn_mfma_f32_16x16x32_bf16(a[0][s], BF[s], pa0##P, 0, 0, 0); \
      pa1##P = __builtin_amdgcn_mfma_f32_16x16x32_bf16(a[1][s], BF[s], pa1##P, 0, 0, 0); \
    }                                                                         \
    __builtin_amdgcn_s_setprio(0);                                            \
  }
#define EXPP(P)                                                               \
  {                                                                           \
    _Pragma("unroll")                                                         \
    for (int r = 0; r < 4; ++r) {                                             \
      psum[0][r] += exp2_hw(pa0##P[r]);                                       \
      psum[1][r] += exp2_hw(pa1##P[r]);                                       \
    }                                                                         \
  }
  LOADB(bfA, 0);
  LOADB(bfB, 1);
  MFMAC(A, bfA);   // cf0 in flight
  LOADB(bfA, 2);
  MFMAC(B, bfB);   // cf1 in flight
  EXPP(A);         // exp2(cf0) overlaps cf1 MFMAs
  LOADB(bfB, 3);
  MFMAC(A, bfA);   // cf2
  EXPP(B);         // exp2(cf1)
  LOADB(bfA, 4);
  MFMAC(B, bfB);   // cf3
  EXPP(A);
  LOADB(bfB, 5);
  MFMAC(A, bfA);   // cf4
  EXPP(B);
  LOADB(bfA, 6);
  MFMAC(B, bfB);   // cf5
  EXPP(A);
  LOADB(bfB, 7);
  MFMAC(A, bfA);   // cf6
  EXPP(B);
  MFMAC(B, bfB);   // cf7
  EXPP(A);
  EXPP(B);
#undef LOADB
#undef MFMAC
#undef EXPP

  // ---- block-level reduce over the 16 l15 lanes sharing each row ----
  // scratch layout: [row 0..255][stride 20 floats] (writes 2-way conflict =
  // free; b128 reads spread evenly over all 32 banks).
  __syncthreads();  // all waves done reading Bt
  #pragma unroll
  for (int rf = 0; rf < 2; ++rf)
    #pragma unroll
    for (int r = 0; r < 4; ++r) {
      const int rowlocal = wave * 32 + rf * 16 + lhi * 4 + r;
      Rs[rowlocal * 20 + l15] = psum[rf][r];
    }
  __syncthreads();
  if (tid < 256) {
    float s = 0.f;
    #pragma unroll
    for (int j = 0; j < 4; ++j) {
      f32x4 vv = *(const f32x4*)&Rs[tid * 20 + j * 4];
      s += vv[0] + vv[1] + vv[2] + vv[3];
    }
    const int row = vy * ry + tid;
    if (ATOMIC) atomicAdd(&out_part[row], s);
    else out_part[(size_t)vx * nrows + row] = s;
  }
}

// ---- combine partials: 8 row-blocks x 8 part-slices ----
__global__ void reduce_kernel(const float* __restrict__ partial, float* __restrict__ rowsum,
                              int nparts, int nrows) {
  const int row = (blockIdx.x & 7) * 256 + threadIdx.x;
  const int slice = blockIdx.x >> 3;
  const int pper = (nparts + 7) / 8;
  const int p0 = slice * pper;
  const int p1 = min(nparts, p0 + pper);
  float s = 0.f;
  #pragma unroll 4
  for (int p = p0; p < p1; ++p) s += partial[(size_t)p * nrows + row];
  atomicAdd(&rowsum[row], s);
}

// ---- finalize: loss = mean( log(down_i) - cosplus_i ) ----
__global__ void finalize_kernel(const float* __restrict__ rowsum, const float* __restrict__ ctv,
                                const float* __restrict__ cpv, float* __restrict__ out,
                                int N, float pad, float invN) {
  const int tid = threadIdx.x;
  float local = 0.f;
  for (int i = tid; i < N; i += 256) {
    float top = __expf(cpv[i]);
    float down = rowsum[i] - pad - __expf(ctv[i]) + top;
    local += __logf(down) - cpv[i];
  }
  #pragma unroll
  for (int m = 32; m; m >>= 1) local += __shfl_xor(local, m);
  __shared__ float red[4];
  if ((tid & 63) == 0) red[tid >> 6] = local;
  __syncthreads();
  if (tid == 0) out[0] = (red[0] + red[1] + red[2] + red[3]) * invN;
}

extern "C" void kernel_launch(void* const* d_in, const int* in_sizes, int n_in,
                              void* d_out, int out_size, void* d_ws, size_t ws_size,
                              hipStream_t stream) {
  const float* features = (const float*)d_in[0];
  const int* target = (const int*)d_in[1];
  const float* w = (const float*)d_in[2];
  float* out = (float*)d_out;

  const int N = in_sizes[1];          // 2048
  const int D = in_sizes[0] / N;      // 128 (layout hardcoded in kernels)
  const int C = in_sizes[2] / D;      // 100000
  (void)D;
  const int nct = (C + 127) / 128;    // 782 col tiles
  const int CT = nct * 128;           // padded col count

  char* ws = (char*)d_ws;
  size_t off = 0;
  unsigned short* Fn = (unsigned short*)(ws + off); off += (size_t)N * 128 * 2;
  float* colinv = (float*)(ws + off); off += (size_t)CT * 4;
  float* rowsum = (float*)(ws + off); off += (size_t)N * 4;
  float* rowinv = (float*)(ws + off); off += (size_t)N * 4;
  float* ctv    = (float*)(ws + off); off += (size_t)N * 4;
  float* cpv    = (float*)(ws + off); off += (size_t)N * 4; off = (off + 255) & ~(size_t)255;
  float* partial = (float*)(ws + off);
  const size_t need_store = off + (size_t)nct * N * 4;
  const size_t wbn_off = (need_store + 255) & ~(size_t)255;
  unsigned short* wbn = (unsigned short*)(ws + wbn_off);
  const size_t need_prep = wbn_off + (size_t)CT * 128 * 2;

  const bool use_store = (ws_size >= need_store);
  const bool use_prep = (ws_size >= need_prep);

  (void)hipMemsetAsync(rowsum, 0, (size_t)N * sizeof(float), stream);
  if (use_prep) {
    colprep_kernel<<<(CT + 255) / 256, 256, 0, stream>>>(w, colinv, wbn, C, CT);
  } else {
    colnorm_kernel<<<(C + 255) / 256, 256, 0, stream>>>(w, colinv, C);
  }
  fnorm_kernel<<<N / 4, 256, 0, stream>>>(features, Fn, rowinv);
  tgtdot_kernel<<<N / 4, 256, 0, stream>>>(features, w, target, rowinv, colinv, ctv, cpv, C);

  dim3 grid(nct, 8);
  if (use_prep && use_store) {
    arc_main_kernel<1, 0><<<grid, 512, 0, stream>>>(w, colinv, wbn, Fn, partial, C, CT, N);
    reduce_kernel<<<64, 256, 0, stream>>>(partial, rowsum, nct, N);
  } else if (use_prep) {
    arc_main_kernel<1, 1><<<grid, 512, 0, stream>>>(w, colinv, wbn, Fn, rowsum, C, CT, N);
  } else if (use_store) {
    arc_main_kernel<0, 0><<<grid, 512, 0, stream>>>(w, colinv, wbn, Fn, partial, C, CT, N);
    reduce_kernel<<<64, 256, 0, stream>>>(partial, rowsum, nct, N);
  } else {
    arc_main_kernel<0, 1><<<grid, 512, 0, stream>>>(w, colinv, wbn, Fn, rowsum, C, CT, N);
  }
  finalize_kernel<<<1, 256, 0, stream>>>(rowsum, ctv, cpv, out, N,
                                         (float)(CT - C), 1.0f / (float)N);
}

// Round 14
// 95.522 us; speedup vs baseline: 1.6018x; 1.1631x over previous
//
#include <hip/hip_runtime.h>
#include <hip/hip_bf16.h>

typedef __attribute__((ext_vector_type(4))) float f32x4;
typedef __attribute__((ext_vector_type(2))) unsigned uintx2;
typedef const __attribute__((address_space(1))) void gvoid_t;
typedef __attribute__((address_space(3))) void lvoid_t;

#define ANGLE_COS 0.8775825618903728f  // cos(0.5)
#define ANGLE_SIN 0.4794255386042030f  // sin(0.5)
#define LOG2E 1.4426950408889634f

static __device__ __forceinline__ float exp2_hw(float x) {
  return __builtin_amdgcn_exp2f(x);  // v_exp_f32: D = 2^S0
}

// pack 4 floats -> 4 OCP e4m3 bytes
static __device__ __forceinline__ unsigned pack4_fp8(float a, float b, float c, float d) {
  int v = __builtin_amdgcn_cvt_pk_fp8_f32(a, b, 0, false);   // bytes 0,1
  v = __builtin_amdgcn_cvt_pk_fp8_f32(c, d, v, true);        // bytes 2,3
  return (unsigned)v;
}

// ---- colprep: column inverse norms + fp8 w_norm*log2e in granule layout:
// granule (q,c) = 8B holding d = q*8..q*8+7 of column c, at wbn + (q*CT+c)*8.
__global__ __launch_bounds__(256) void colprep_kernel(
    const float* __restrict__ w, float* __restrict__ colinv,
    unsigned char* __restrict__ wbn, int C, int CT) {
  const int c = blockIdx.x * 256 + threadIdx.x;
  if (c >= CT) return;
  if (c >= C) {  // pad columns -> zeros (2^0=1, subtracted in finalize)
    colinv[c] = 0.f;
    uintx2 z; z.x = 0; z.y = 0;
    #pragma unroll
    for (int q = 0; q < 16; ++q) *(uintx2*)(wbn + ((size_t)q * CT + c) * 8) = z;
    return;
  }
  float col[128];
  float s = 0.f;
  #pragma unroll
  for (int d = 0; d < 128; ++d) {
    col[d] = w[(size_t)d * C + c];
    s += col[d] * col[d];
  }
  const float inv = 1.0f / sqrtf(s);
  colinv[c] = inv;
  const float invl = inv * LOG2E;
  #pragma unroll
  for (int q = 0; q < 16; ++q) {
    uintx2 g;
    g.x = pack4_fp8(col[q*8+0]*invl, col[q*8+1]*invl, col[q*8+2]*invl, col[q*8+3]*invl);
    g.y = pack4_fp8(col[q*8+4]*invl, col[q*8+5]*invl, col[q*8+6]*invl, col[q*8+7]*invl);
    *(uintx2*)(wbn + ((size_t)q * CT + c) * 8) = g;
  }
}

// ---- colnorm only (fallback path when ws can't hold wbn) ----
__global__ void colnorm_kernel(const float* __restrict__ w, float* __restrict__ colinv, int C) {
  int c = blockIdx.x * 256 + threadIdx.x;
  if (c >= C) return;
  float s = 0.f;
  #pragma unroll 8
  for (int d = 0; d < 128; ++d) { float v = w[(size_t)d * C + c]; s += v * v; }
  colinv[c] = 1.0f / sqrtf(s);
}

// ---- row-normalize features -> fp8 Fn (row-major, 128 B/row) ----
__global__ void fnorm_kernel(const float* __restrict__ f, unsigned char* __restrict__ Fn,
                             float* __restrict__ rowinv) {
  const int wave = threadIdx.x >> 6, lane = threadIdx.x & 63;
  const int row = blockIdx.x * 4 + wave;
  const float* fr = f + (size_t)row * 128;
  float x0 = fr[2 * lane], x1 = fr[2 * lane + 1];
  float s = x0 * x0 + x1 * x1;
  #pragma unroll
  for (int m = 32; m; m >>= 1) s += __shfl_xor(s, m);
  float inv = 1.0f / sqrtf(s);
  unsigned p = (unsigned)__builtin_amdgcn_cvt_pk_fp8_f32(x0 * inv, x1 * inv, 0, false);
  *(unsigned short*)(Fn + (size_t)row * 128 + lane * 2) = (unsigned short)(p & 0xFFFFu);
  if (lane == 0) rowinv[row] = inv;
}

// ---- fp32 dot with the target column: ct and cos(theta+m) per row ----
__global__ void tgtdot_kernel(const float* __restrict__ f, const float* __restrict__ w,
                              const int* __restrict__ target, const float* __restrict__ rowinv,
                              const float* __restrict__ colinv, float* __restrict__ ctv,
                              float* __restrict__ cpv, int C) {
  const int wave = threadIdx.x >> 6, lane = threadIdx.x & 63;
  const int row = blockIdx.x * 4 + wave;
  const int t = target[row];
  const float* fr = f + (size_t)row * 128;
  float s = fr[lane] * w[(size_t)lane * C + t] + fr[lane + 64] * w[(size_t)(lane + 64) * C + t];
  #pragma unroll
  for (int m = 32; m; m >>= 1) s += __shfl_xor(s, m);
  if (lane == 0) {
    float ct = s * rowinv[row] * colinv[t];
    ct = fminf(1.f, fmaxf(-1.f, ct));
    float st = sqrtf(fmaxf(0.f, 1.f - ct * ct));
    ctv[row] = ct;
    cpv[row] = ct * ANGLE_COS - st * ANGLE_SIN;
  }
}

// ---- main: R11 geometry/structure (512 thr / 8 waves, rf=2, 128-col tile,
// grid (782,8)), fp8 operands (R14): B tile 16 KB in LDS, ds_read_b64 frags
// (half the LDS traffic of bf16 — R13 audit: LDS was the largest pipe floor
// at ~31us), fp8_fp8 MFMA at the bf16 rate. Target column stays fp32.
template <int PREP, int ATOMIC>
__global__ __launch_bounds__(512) void arc_main_kernel(
    const float* __restrict__ w, const float* __restrict__ colinv,
    const unsigned char* __restrict__ wbn, const unsigned char* __restrict__ Fn,
    float* __restrict__ out_part, int C, int CT, int nrows) {
  __shared__ __align__(16) char smem[20480];  // max(16KB tile, 20KB reduce)
  char* Bt = smem;
  float* Rs = (float*)smem;  // reduce scratch, reused after barrier
  const int tid = threadIdx.x;

  // bijective XCD swizzle (total = nx*8): each col-tile's 8 row-groups get
  // consecutive virtual ids on one XCD -> tile L2-hot across its stagings.
  const int nx = gridDim.x;
  const int i = blockIdx.x + nx * blockIdx.y;  // hw linear id (x fastest)
  const int v = (i & 7) * nx + (i >> 3);       // XCD-contiguous virtual id
  const int vx = v >> 3;                       // col-tile
  const int vy = v & 7;                        // row-group
  const int cbase = vx << 7;

  const int wave = tid >> 6;
  const int lane = tid & 63;
  const int l15 = lane & 15;
  const int lhi = lane >> 4;
  const int ry = nrows >> 3;               // rows per row-group (256)
  const int rowbase = vy * ry + wave * 32; // 32 rows per wave

  if (PREP) {
    // 16 KB tile: wave handles q = wave, wave+8; each q-chunk is 1 KB
    // contiguous in wbn (128 granules x 8B). dest = uniform base + lane*16.
    #pragma unroll
    for (int k = 0; k < 2; ++k) {
      const int q = wave + k * 8;
      __builtin_amdgcn_global_load_lds(
          (gvoid_t*)(const void*)(wbn + ((size_t)q * CT + cbase) * 8 + lane * 16),
          (lvoid_t*)(void*)(Bt + q * 1024 + lane * 16), 16, 0, 0);
    }
  } else {
    const int c = tid & 127;
    const int dstart = tid >> 7;  // 0..3
    const int gc = cbase + c;
    const bool ok = (gc < C);
    const float cinv = ok ? colinv[gc] * LOG2E : 0.f;
    const float* wp = w + (size_t)dstart * C + gc;
    #pragma unroll 8
    for (int s = 0; s < 32; ++s) {
      const int d = dstart + 4 * s;
      float vv = ok ? wp[(size_t)(4 * s) * C] * cinv : 0.f;
      Bt[(d >> 3) * 1024 + c * 8 + (d & 7)] =
          (char)(__builtin_amdgcn_cvt_pk_fp8_f32(vv, 0.f, 0, false) & 0xFF);
    }
  }

  // A fragments (fp8: 8B per frag) issued BEFORE the barrier.
  long a[2][4];
  {
    const char* base = (const char*)Fn + (size_t)(rowbase + l15) * 128 + lhi * 8;
    #pragma unroll
    for (int rf = 0; rf < 2; ++rf)
      #pragma unroll
      for (int s = 0; s < 4; ++s)
        a[rf][s] = *(const long*)(base + rf * 16 * 128 + s * 32);
  }
  __syncthreads();

  float psum[2][4];
  #pragma unroll
  for (int rf = 0; rf < 2; ++rf)
    #pragma unroll
    for (int r = 0; r < 4; ++r) psum[rf][r] = 0.f;

  // double-buffered cf pipeline over 8 col-frags (16 cols each); ds_read_b64
  // frags: bank = 2*(lane&15) -> 4 lanes/bank-pair = b64 minimum (free).
  long bfA[4], bfB[4];
#define LOADB(DST, CF)                                                        \
  {                                                                           \
    const char* bcol = Bt + ((CF) * 16 + l15) * 8;                            \
    _Pragma("unroll")                                                         \
    for (int s = 0; s < 4; ++s)                                               \
      DST[s] = *(const long*)(bcol + (s * 4 + lhi) * 1024);                   \
  }
#define COMPUTE(BF)                                                           \
  {                                                                           \
    f32x4 acc0 = (f32x4){0.f, 0.f, 0.f, 0.f};                                 \
    f32x4 acc1 = (f32x4){0.f, 0.f, 0.f, 0.f};                                 \
    __builtin_amdgcn_s_setprio(1);                                            \
    _Pragma("unroll")                                                         \
    for (int s = 0; s < 4; ++s) {                                             \
      acc0 = __builtin_amdgcn_mfma_f32_16x16x32_fp8_fp8(a[0][s], BF[s], acc0, 0, 0, 0); \
      acc1 = __builtin_amdgcn_mfma_f32_16x16x32_fp8_fp8(a[1][s], BF[s], acc1, 0, 0, 0); \
    }                                                                         \
    __builtin_amdgcn_s_setprio(0);                                            \
    _Pragma("unroll")                                                         \
    for (int r = 0; r < 4; ++r) {                                             \
      psum[0][r] += exp2_hw(acc0[r]);                                         \
      psum[1][r] += exp2_hw(acc1[r]);                                         \
    }                                                                         \
  }
  LOADB(bfA, 0);
  LOADB(bfB, 1);
  COMPUTE(bfA);            // cf 0 (bfB already in flight)
  LOADB(bfA, 2);
  COMPUTE(bfB);            // cf 1
  LOADB(bfB, 3);
  COMPUTE(bfA);            // cf 2
  LOADB(bfA, 4);
  COMPUTE(bfB);            // cf 3
  LOADB(bfB, 5);
  COMPUTE(bfA);            // cf 4
  LOADB(bfA, 6);
  COMPUTE(bfB);            // cf 5
  LOADB(bfB, 7);
  COMPUTE(bfA);            // cf 6
  COMPUTE(bfB);            // cf 7
#undef LOADB
#undef COMPUTE

  // ---- block-level reduce over the 16 l15 lanes sharing each row ----
  // scratch: [row 0..255][stride 20 floats] = 20480 B.
  __syncthreads();  // all waves done reading Bt
  #pragma unroll
  for (int rf = 0; rf < 2; ++rf)
    #pragma unroll
    for (int r = 0; r < 4; ++r) {
      const int rowlocal = wave * 32 + rf * 16 + lhi * 4 + r;
      Rs[rowlocal * 20 + l15] = psum[rf][r];
    }
  __syncthreads();
  if (tid < 256) {
    float s = 0.f;
    #pragma unroll
    for (int j = 0; j < 4; ++j) {
      f32x4 vv = *(const f32x4*)&Rs[tid * 20 + j * 4];
      s += vv[0] + vv[1] + vv[2] + vv[3];
    }
    const int row = vy * ry + tid;
    if (ATOMIC) atomicAdd(&out_part[row], s);
    else out_part[(size_t)vx * nrows + row] = s;
  }
}

// ---- combine partials: 8 row-blocks x 8 part-slices ----
__global__ void reduce_kernel(const float* __restrict__ partial, float* __restrict__ rowsum,
                              int nparts, int nrows) {
  const int row = (blockIdx.x & 7) * 256 + threadIdx.x;
  const int slice = blockIdx.x >> 3;
  const int pper = (nparts + 7) / 8;
  const int p0 = slice * pper;
  const int p1 = min(nparts, p0 + pper);
  float s = 0.f;
  #pragma unroll 4
  for (int p = p0; p < p1; ++p) s += partial[(size_t)p * nrows + row];
  atomicAdd(&rowsum[row], s);
}

// ---- finalize: loss = mean( log(down_i) - cosplus_i ) ----
__global__ void finalize_kernel(const float* __restrict__ rowsum, const float* __restrict__ ctv,
                                const float* __restrict__ cpv, float* __restrict__ out,
                                int N, float pad, float invN) {
  const int tid = threadIdx.x;
  float local = 0.f;
  for (int i = tid; i < N; i += 256) {
    float top = __expf(cpv[i]);
    float down = rowsum[i] - pad - __expf(ctv[i]) + top;
    local += __logf(down) - cpv[i];
  }
  #pragma unroll
  for (int m = 32; m; m >>= 1) local += __shfl_xor(local, m);
  __shared__ float red[4];
  if ((tid & 63) == 0) red[tid >> 6] = local;
  __syncthreads();
  if (tid == 0) out[0] = (red[0] + red[1] + red[2] + red[3]) * invN;
}

extern "C" void kernel_launch(void* const* d_in, const int* in_sizes, int n_in,
                              void* d_out, int out_size, void* d_ws, size_t ws_size,
                              hipStream_t stream) {
  const float* features = (const float*)d_in[0];
  const int* target = (const int*)d_in[1];
  const float* w = (const float*)d_in[2];
  float* out = (float*)d_out;

  const int N = in_sizes[1];          // 2048
  const int D = in_sizes[0] / N;      // 128 (layout hardcoded in kernels)
  const int C = in_sizes[2] / D;      // 100000
  (void)D;
  const int nct = (C + 127) / 128;    // 782 col tiles
  const int CT = nct * 128;           // padded col count

  char* ws = (char*)d_ws;
  size_t off = 0;
  unsigned char* Fn = (unsigned char*)(ws + off); off += (size_t)N * 128;
  off = (off + 255) & ~(size_t)255;
  float* colinv = (float*)(ws + off); off += (size_t)CT * 4;
  float* rowsum = (float*)(ws + off); off += (size_t)N * 4;
  float* rowinv = (float*)(ws + off); off += (size_t)N * 4;
  float* ctv    = (float*)(ws + off); off += (size_t)N * 4;
  float* cpv    = (float*)(ws + off); off += (size_t)N * 4; off = (off + 255) & ~(size_t)255;
  float* partial = (float*)(ws + off);
  const size_t need_store = off + (size_t)nct * N * 4;
  const size_t wbn_off = (need_store + 255) & ~(size_t)255;
  unsigned char* wbn = (unsigned char*)(ws + wbn_off);
  const size_t need_prep = wbn_off + (size_t)CT * 128;

  const bool use_store = (ws_size >= need_store);
  const bool use_prep = (ws_size >= need_prep);

  (void)hipMemsetAsync(rowsum, 0, (size_t)N * sizeof(float), stream);
  if (use_prep) {
    colprep_kernel<<<(CT + 255) / 256, 256, 0, stream>>>(w, colinv, wbn, C, CT);
  } else {
    colnorm_kernel<<<(C + 255) / 256, 256, 0, stream>>>(w, colinv, C);
  }
  fnorm_kernel<<<N / 4, 256, 0, stream>>>(features, Fn, rowinv);
  tgtdot_kernel<<<N / 4, 256, 0, stream>>>(features, w, target, rowinv, colinv, ctv, cpv, C);

  dim3 grid(nct, 8);
  if (use_prep && use_store) {
    arc_main_kernel<1, 0><<<grid, 512, 0, stream>>>(w, colinv, wbn, Fn, partial, C, CT, N);
    reduce_kernel<<<64, 256, 0, stream>>>(partial, rowsum, nct, N);
  } else if (use_prep) {
    arc_main_kernel<1, 1><<<grid, 512, 0, stream>>>(w, colinv, wbn, Fn, rowsum, C, CT, N);
  } else if (use_store) {
    arc_main_kernel<0, 0><<<grid, 512, 0, stream>>>(w, colinv, wbn, Fn, partial, C, CT, N);
    reduce_kernel<<<64, 256, 0, stream>>>(partial, rowsum, nct, N);
  } else {
    arc_main_kernel<0, 1><<<grid, 512, 0, stream>>>(w, colinv, wbn, Fn, rowsum, C, CT, N);
  }
  finalize_kernel<<<1, 256, 0, stream>>>(rowsum, ctv, cpv, out, N,
                                         (float)(CT - C), 1.0f / (float)N);
}